// Round 1
// baseline (1662.795 us; speedup 1.0000x reference)
//
#include <hip/hip_runtime.h>
#include <cstdint>
#include <cstddef>

constexpr int Bn = 64, Tn = 1024, Hn = 256, Kn = 4;
constexpr int MROWS = 32;           // output t-rows per block
constexpr int SROWS = MROWS + 2;    // staged input rows (t0-1 .. t0+MROWS)
constexpr int SST   = SROWS + 1;    // LDS row stride (pad) = 35

// Pack conv_w [o][i][dt] -> wP[(dt*256+i)][o]  (GEMM-friendly B matrix)
__global__ __launch_bounds__(256) void pack_w_k(const float* __restrict__ conv_w,
                                                float* __restrict__ wP) {
  int o  = threadIdx.x;
  int kk = blockIdx.x;              // kk = dt*256 + i
  int dt = kk >> 8, i = kk & 255;
  wP[kk * Hn + o] = conv_w[o * (Hn * 3) + i * 3 + dt];
}

// Fused conv1d(k=3,pad=1) + bias + ReLU + Linear(256->4): writes em[B,T,4] fp32
__global__ __launch_bounds__(256) void emis_k(const float* __restrict__ x,
    const float* __restrict__ wP, const float* __restrict__ conv_b,
    const float* __restrict__ lin_w, const float* __restrict__ lin_b,
    float* __restrict__ em) {
  __shared__ float xsT[Hn * SST];   // [i][row], 256*35*4 = 35840 B
  const int b  = blockIdx.y, tt = blockIdx.x;
  const int t0 = tt * MROWS;
  const int tid = threadIdx.x;
  const int tx = tid & 15, ty = tid >> 4;

  // Stage A (input rows t0-1 .. t0+32, all 256 channels), transposed [i][row]
  const float4* x4 = reinterpret_cast<const float4*>(x + (size_t)b * Tn * Hn);
  for (int idx = tid; idx < SROWS * (Hn / 4); idx += 256) {
    int row = idx >> 6, c4 = idx & 63;
    int t = t0 - 1 + row;
    float4 v = make_float4(0.f, 0.f, 0.f, 0.f);
    if (t >= 0 && t < Tn) v = x4[t * (Hn / 4) + c4];
    int i = c4 << 2;
    xsT[(i + 0) * SST + row] = v.x;
    xsT[(i + 1) * SST + row] = v.y;
    xsT[(i + 2) * SST + row] = v.z;
    xsT[(i + 3) * SST + row] = v.w;
  }
  __syncthreads();

  // Each thread: rows m = ty + 16r (r=0,1), cols n = tx*16 .. +15
  float acc[2][16];
  #pragma unroll
  for (int r = 0; r < 2; ++r)
    #pragma unroll
    for (int j = 0; j < 16; ++j) acc[r][j] = 0.f;

  #pragma unroll 1
  for (int dt = 0; dt < 3; ++dt) {
    const float* wbase = wP + (size_t)(dt << 8) * Hn + (tx << 4);
    const int abase = ty + dt;
    #pragma unroll 2
    for (int i = 0; i < 256; ++i) {
      const float a0 = xsT[i * SST + abase];
      const float a1 = xsT[i * SST + abase + 16];
      const float* wr = wbase + i * Hn;
      const float4 b0 = *reinterpret_cast<const float4*>(wr);
      const float4 b1 = *reinterpret_cast<const float4*>(wr + 4);
      const float4 b2 = *reinterpret_cast<const float4*>(wr + 8);
      const float4 b3 = *reinterpret_cast<const float4*>(wr + 12);
      float bb[16] = {b0.x, b0.y, b0.z, b0.w, b1.x, b1.y, b1.z, b1.w,
                      b2.x, b2.y, b2.z, b2.w, b3.x, b3.y, b3.z, b3.w};
      #pragma unroll
      for (int j = 0; j < 16; ++j) {
        acc[0][j] = fmaf(a0, bb[j], acc[0][j]);
        acc[1][j] = fmaf(a1, bb[j], acc[1][j]);
      }
    }
  }

  // Epilogue: +conv_b, ReLU, x lin_w^T partial sums over this thread's 16 cols
  float pem[2][4];
  #pragma unroll
  for (int r = 0; r < 2; ++r)
    #pragma unroll
    for (int k = 0; k < 4; ++k) pem[r][k] = 0.f;

  const int n0 = tx << 4;
  #pragma unroll
  for (int j = 0; j < 16; ++j) {
    const int n = n0 + j;
    const float cb = conv_b[n];
    const float l0 = lin_w[0 * Hn + n];
    const float l1 = lin_w[1 * Hn + n];
    const float l2 = lin_w[2 * Hn + n];
    const float l3 = lin_w[3 * Hn + n];
    #pragma unroll
    for (int r = 0; r < 2; ++r) {
      float v = acc[r][j] + cb;
      v = fmaxf(v, 0.f);
      pem[r][0] = fmaf(v, l0, pem[r][0]);
      pem[r][1] = fmaf(v, l1, pem[r][1]);
      pem[r][2] = fmaf(v, l2, pem[r][2]);
      pem[r][3] = fmaf(v, l3, pem[r][3]);
    }
  }
  // Reduce over the 16 tx lanes (same wave: lane bits 0..3)
  #pragma unroll
  for (int r = 0; r < 2; ++r)
    #pragma unroll
    for (int k = 0; k < 4; ++k) {
      float v = pem[r][k];
      v += __shfl_xor(v, 1);
      v += __shfl_xor(v, 2);
      v += __shfl_xor(v, 4);
      v += __shfl_xor(v, 8);
      pem[r][k] = v;
    }
  if (tx == 0) {
    #pragma unroll
    for (int r = 0; r < 2; ++r) {
      int m = ty + 16 * r;
      float4 o;
      o.x = pem[r][0] + lin_b[0];
      o.y = pem[r][1] + lin_b[1];
      o.z = pem[r][2] + lin_b[2];
      o.w = pem[r][3] + lin_b[3];
      *reinterpret_cast<float4*>(em + (size_t)(b * Tn + t0 + m) * 4) = o;
    }
  }
}

// CRF Viterbi decode, one block per batch, serial scan on thread 0.
// Bitwise-faithful to reference: cand = (score[j] + trans[j][k]) + em[t][k],
// first-occurrence-wins argmax (strict >).
__global__ __launch_bounds__(64) void viterbi_k(const float* __restrict__ em,
    const float* __restrict__ cstart, const float* __restrict__ cend,
    const float* __restrict__ ctrans, int* __restrict__ out) {
  __shared__ float4 se[Tn];              // 16 KB emissions for this batch
  __shared__ unsigned int hist[Tn - 1];  // 4 packed argmax tags per step
  const int b = blockIdx.x, tid = threadIdx.x;
  const float4* e4 = reinterpret_cast<const float4*>(em + (size_t)b * Tn * Kn);
  for (int i = tid; i < Tn; i += 64) se[i] = e4[i];
  __syncthreads();
  if (tid == 0) {
    float tr[4][4];
    #pragma unroll
    for (int j = 0; j < 4; ++j)
      #pragma unroll
      for (int k = 0; k < 4; ++k) tr[j][k] = ctrans[j * 4 + k];
    float4 e0 = se[0];
    float s[4] = { cstart[0] + e0.x, cstart[1] + e0.y,
                   cstart[2] + e0.z, cstart[3] + e0.w };
    float4 eA = se[1];
    float4 eB = se[2];
    for (int t = 1; t < Tn; ++t) {
      float4 e = eA;
      eA = eB;
      if (t + 2 < Tn) eB = se[t + 2];
      float ev[4] = { e.x, e.y, e.z, e.w };
      float ns[4];
      unsigned int hw = 0;
      #pragma unroll
      for (int k = 0; k < 4; ++k) {
        float best = (s[0] + tr[0][k]) + ev[k];
        int bi = 0;
        #pragma unroll
        for (int j = 1; j < 4; ++j) {
          float c = (s[j] + tr[j][k]) + ev[k];
          if (c > best) { best = c; bi = j; }
        }
        ns[k] = best;
        hw |= (unsigned)bi << (8 * k);
      }
      hist[t - 1] = hw;
      s[0] = ns[0]; s[1] = ns[1]; s[2] = ns[2]; s[3] = ns[3];
    }
    #pragma unroll
    for (int k = 0; k < 4; ++k) s[k] += cend[k];
    int tag = 0;
    float bf = s[0];
    #pragma unroll
    for (int k = 1; k < 4; ++k) if (s[k] > bf) { bf = s[k]; tag = k; }
    int* ob = out + (size_t)b * Tn;
    ob[Tn - 1] = tag;
    for (int t = Tn - 2; t >= 0; --t) {
      tag = (int)((hist[t] >> (tag * 8)) & 3u);
      ob[t] = tag;
    }
  }
}

extern "C" void kernel_launch(void* const* d_in, const int* in_sizes, int n_in,
                              void* d_out, int out_size, void* d_ws, size_t ws_size,
                              hipStream_t stream) {
  const float* x      = (const float*)d_in[0];
  const float* conv_w = (const float*)d_in[1];
  const float* conv_b = (const float*)d_in[2];
  const float* lin_w  = (const float*)d_in[3];
  const float* lin_b  = (const float*)d_in[4];
  const float* cstart = (const float*)d_in[5];
  const float* cend   = (const float*)d_in[6];
  const float* ctrans = (const float*)d_in[7];
  int* out = (int*)d_out;

  float* wP = (float*)d_ws;                      // 768*256 floats (768 KB)
  float* em = wP + 768 * 256;                    // 64*1024*4 floats (1 MB)

  pack_w_k<<<768, 256, 0, stream>>>(conv_w, wP);
  emis_k<<<dim3(Tn / MROWS, Bn), 256, 0, stream>>>(x, wP, conv_b, lin_w, lin_b, em);
  viterbi_k<<<Bn, 64, 0, stream>>>(em, cstart, cend, ctrans, out);
}

// Round 2
// 495.565 us; speedup vs baseline: 3.3554x; 3.3554x over previous
//
#include <hip/hip_runtime.h>
#include <cstdint>
#include <cstddef>

constexpr int Bn = 64, Tn = 1024, Hn = 256, Kn = 4;
constexpr int MROWS = 32;           // output t-rows per block
constexpr int SROWS = MROWS + 2;    // staged input rows
constexpr int SST   = 36;           // LDS row stride (16B-aligned, 34 used)
constexpr int CHI   = 4;            // i-values per B chunk
constexpr int NCH   = Hn / CHI;     // 64 chunks

// Pack conv_w [o][i][dt] -> wP[(dt*256+i)][o]
__global__ __launch_bounds__(256) void pack_w_k(const float* __restrict__ conv_w,
                                                float* __restrict__ wP) {
  int o  = threadIdx.x;
  int kk = blockIdx.x;              // kk = dt*256 + i
  int dt = kk >> 8, i = kk & 255;
  wP[kk * Hn + o] = conv_w[o * (Hn * 3) + i * 3 + dt];
}

// Fused conv1d(k=3,pad=1) + bias + ReLU + Linear(256->4): em[B,T,4] fp32
// C-tile 32(t) x 256(n); A staged transposed in LDS; B staged in LDS,
// double-buffered 4-i chunks (3 dt planes each).
__global__ __launch_bounds__(256, 2) void emis_k(const float* __restrict__ x,
    const float* __restrict__ wP, const float* __restrict__ conv_b,
    const float* __restrict__ lin_w, const float* __restrict__ lin_b,
    float* __restrict__ em) {
  __shared__ float xsT[Hn * SST];        // [i][row], 36,864 B
  __shared__ float bufB[2][3 * CHI][Hn]; // 24,576 B

  const int b  = blockIdx.y, t0 = blockIdx.x * MROWS;
  const int tid = threadIdx.x;
  const int ng = tid & 31;          // n-group: cols ng*8 .. +7
  const int mg = tid >> 5;          // m-group: rows 4*mg .. +3

  // ---- Stage A transposed: [i][row], rows = t0-1 .. t0+32 ----
  const float4* x4 = reinterpret_cast<const float4*>(x + (size_t)b * Tn * Hn);
  for (int idx = tid; idx < SROWS * (Hn / 4); idx += 256) {
    int row = idx >> 6, c4 = idx & 63;
    int t = t0 - 1 + row;
    float4 v = make_float4(0.f, 0.f, 0.f, 0.f);
    if (t >= 0 && t < Tn) v = x4[t * (Hn / 4) + c4];
    int i = c4 << 2;
    xsT[(i + 0) * SST + row] = v.x;
    xsT[(i + 1) * SST + row] = v.y;
    xsT[(i + 2) * SST + row] = v.z;
    xsT[(i + 3) * SST + row] = v.w;
  }

  // ---- Stage B chunk 0 ----
  const float4* w4 = reinterpret_cast<const float4*>(wP);
  const int h = tid >> 6, c4v = tid & 63;   // thread owns rows dt*4+h, lane col c4v
  float4 pre0 = w4[(0 * 256 + 0 + h) * 64 + c4v];
  float4 pre1 = w4[(1 * 256 + 0 + h) * 64 + c4v];
  float4 pre2 = w4[(2 * 256 + 0 + h) * 64 + c4v];
  *reinterpret_cast<float4*>(&bufB[0][0 + h][c4v * 4]) = pre0;
  *reinterpret_cast<float4*>(&bufB[0][4 + h][c4v * 4]) = pre1;
  *reinterpret_cast<float4*>(&bufB[0][8 + h][c4v * 4]) = pre2;
  __syncthreads();

  float acc[4][8];
  #pragma unroll
  for (int rr = 0; rr < 4; ++rr)
    #pragma unroll
    for (int j = 0; j < 8; ++j) acc[rr][j] = 0.f;

  #pragma unroll 1
  for (int c = 0; c < NCH; ++c) {
    const int cur = c & 1;
    const bool more = (c + 1 < NCH);
    if (more) {   // issue next-chunk global loads early (hide L2 latency)
      const int i0n = (c + 1) * CHI;
      pre0 = w4[(0 * 256 + i0n + h) * 64 + c4v];
      pre1 = w4[(1 * 256 + i0n + h) * 64 + c4v];
      pre2 = w4[(2 * 256 + i0n + h) * 64 + c4v];
    }
    #pragma unroll
    for (int ii = 0; ii < CHI; ++ii) {
      const int i = c * CHI + ii;
      const float* ap = &xsT[i * SST + 4 * mg];
      const float4 a01 = *reinterpret_cast<const float4*>(ap);
      const float2 a2  = *reinterpret_cast<const float2*>(ap + 4);
      const float a[6] = {a01.x, a01.y, a01.z, a01.w, a2.x, a2.y};
      #pragma unroll
      for (int dt = 0; dt < 3; ++dt) {
        const float* bp = &bufB[cur][dt * 4 + ii][ng * 8];
        const float4 b0 = *reinterpret_cast<const float4*>(bp);
        const float4 b1 = *reinterpret_cast<const float4*>(bp + 4);
        const float bb[8] = {b0.x, b0.y, b0.z, b0.w, b1.x, b1.y, b1.z, b1.w};
        #pragma unroll
        for (int rr = 0; rr < 4; ++rr)
          #pragma unroll
          for (int j = 0; j < 8; ++j)
            acc[rr][j] = fmaf(a[rr + dt], bb[j], acc[rr][j]);
      }
    }
    if (more) {   // write-late: staged after compute, before barrier (T14)
      *reinterpret_cast<float4*>(&bufB[cur ^ 1][0 + h][c4v * 4]) = pre0;
      *reinterpret_cast<float4*>(&bufB[cur ^ 1][4 + h][c4v * 4]) = pre1;
      *reinterpret_cast<float4*>(&bufB[cur ^ 1][8 + h][c4v * 4]) = pre2;
    }
    __syncthreads();
  }

  // ---- Epilogue: +conv_b, ReLU, x lin_w^T, reduce over 32 ng lanes ----
  float pem[4][4];
  #pragma unroll
  for (int rr = 0; rr < 4; ++rr)
    #pragma unroll
    for (int k = 0; k < 4; ++k) pem[rr][k] = 0.f;

  #pragma unroll
  for (int j = 0; j < 8; ++j) {
    const int n = ng * 8 + j;
    const float cb = conv_b[n];
    const float l0 = lin_w[0 * Hn + n];
    const float l1 = lin_w[1 * Hn + n];
    const float l2 = lin_w[2 * Hn + n];
    const float l3 = lin_w[3 * Hn + n];
    #pragma unroll
    for (int rr = 0; rr < 4; ++rr) {
      float v = fmaxf(acc[rr][j] + cb, 0.f);
      pem[rr][0] = fmaf(v, l0, pem[rr][0]);
      pem[rr][1] = fmaf(v, l1, pem[rr][1]);
      pem[rr][2] = fmaf(v, l2, pem[rr][2]);
      pem[rr][3] = fmaf(v, l3, pem[rr][3]);
    }
  }
  #pragma unroll
  for (int rr = 0; rr < 4; ++rr)
    #pragma unroll
    for (int k = 0; k < 4; ++k) {
      float v = pem[rr][k];
      v += __shfl_xor(v, 1);
      v += __shfl_xor(v, 2);
      v += __shfl_xor(v, 4);
      v += __shfl_xor(v, 8);
      v += __shfl_xor(v, 16);
      pem[rr][k] = v;
    }
  if (ng == 0) {
    #pragma unroll
    for (int rr = 0; rr < 4; ++rr) {
      const int m = 4 * mg + rr;
      float4 o;
      o.x = pem[rr][0] + lin_b[0];
      o.y = pem[rr][1] + lin_b[1];
      o.z = pem[rr][2] + lin_b[2];
      o.w = pem[rr][3] + lin_b[3];
      *reinterpret_cast<float4*>(em + (size_t)(b * Tn + t0 + m) * 4) = o;
    }
  }
}

// byte-map composition c(k) = a(b(k)); map byte values are 0..3 so
// v_perm with both data operands = a is convention-proof.
__device__ __forceinline__ unsigned int compose_map(unsigned int a, unsigned int b) {
#if __has_builtin(__builtin_amdgcn_perm)
  return __builtin_amdgcn_perm(a, a, b);
#else
  unsigned int c = 0;
  #pragma unroll
  for (int k = 0; k < 4; ++k) {
    unsigned int sel = (b >> (8 * k)) & 0xffu;
    c |= ((a >> (8 * sel)) & 0xffu) << (8 * k);
  }
  return c;
#endif
}

// CRF Viterbi decode. Forward: serial max-only scan on lane 0 (stores the
// running score vector per step, bitwise-identical candidate math to ref).
// Backtrace: 64 lanes rebuild argmax maps (identical fp expressions ->
// identical argmax), compose via v_perm suffix-scan (integer-exact).
__global__ __launch_bounds__(64) void viterbi_k(const float* __restrict__ em,
    const float* __restrict__ cstart, const float* __restrict__ cend,
    const float* __restrict__ ctrans, int* __restrict__ out) {
  __shared__ float4 se[Tn];          // emissions, 16 KB
  __shared__ float4 sh[Tn - 1];      // score vector BEFORE step t+1, 16 KB
  __shared__ int s_last;
  const int b = blockIdx.x, lane = threadIdx.x;
  const float4* e4 = reinterpret_cast<const float4*>(em + (size_t)b * Tn * Kn);
  for (int i = lane; i < Tn; i += 64) se[i] = e4[i];
  float tr[4][4];
  #pragma unroll
  for (int j = 0; j < 4; ++j)
    #pragma unroll
    for (int k = 0; k < 4; ++k) tr[j][k] = ctrans[j * 4 + k];
  __syncthreads();

  if (lane == 0) {
    float4 e0 = se[0];
    float s0 = cstart[0] + e0.x, s1 = cstart[1] + e0.y;
    float s2 = cstart[2] + e0.z, s3 = cstart[3] + e0.w;
    float4 eA = se[1], eB = se[2];
    for (int t = 1; t < Tn; ++t) {
      const float4 e = eA;
      eA = eB;
      if (t + 2 < Tn) eB = se[t + 2];
      sh[t - 1] = make_float4(s0, s1, s2, s3);
      const float ev[4] = {e.x, e.y, e.z, e.w};
      float ns[4];
      #pragma unroll
      for (int k = 0; k < 4; ++k) {
        float m01 = fmaxf((s0 + tr[0][k]) + ev[k], (s1 + tr[1][k]) + ev[k]);
        float m23 = fmaxf((s2 + tr[2][k]) + ev[k], (s3 + tr[3][k]) + ev[k]);
        ns[k] = fmaxf(m01, m23);
      }
      s0 = ns[0]; s1 = ns[1]; s2 = ns[2]; s3 = ns[3];
    }
    s0 += cend[0]; s1 += cend[1]; s2 += cend[2]; s3 += cend[3];
    int tag = 0; float bf = s0;
    if (s1 > bf) { bf = s1; tag = 1; }
    if (s2 > bf) { bf = s2; tag = 2; }
    if (s3 > bf) { bf = s3; tag = 3; }
    s_last = tag;
  }
  __syncthreads();

  // ---- parallel backtrace: lane owns maps t in [16*lane, 16*lane+15] ----
  const unsigned int ID = 0x03020100u;
  unsigned int mloc[16];
  const int t0 = lane * 16;
  #pragma unroll
  for (int k = 0; k < 16; ++k) {
    const int t = t0 + k;
    if (t < Tn - 1) {
      const float4 s = sh[t];
      const float4 e = se[t + 1];
      const float sj[4] = {s.x, s.y, s.z, s.w};
      const float ev[4] = {e.x, e.y, e.z, e.w};
      unsigned int mw = 0;
      #pragma unroll
      for (int kk = 0; kk < 4; ++kk) {
        float best = (sj[0] + tr[0][kk]) + ev[kk];
        int bi = 0;
        #pragma unroll
        for (int j = 1; j < 4; ++j) {
          float cc = (sj[j] + tr[j][kk]) + ev[kk];
          if (cc > best) { best = cc; bi = j; }
        }
        mw |= (unsigned)bi << (8 * kk);
      }
      mloc[k] = mw;
    } else {
      mloc[k] = ID;
    }
  }
  // within-lane composition: P = m[t0] o m[t0+1] o ... o m[t0+15]
  unsigned int P = mloc[15];
  #pragma unroll
  for (int k = 14; k >= 0; --k) P = compose_map(mloc[k], P);
  // suffix scan across lanes: P_L = M_L o M_{L+1} o ... o M_63
  #pragma unroll
  for (int d = 1; d < 64; d <<= 1) {
    unsigned int q = (unsigned int)__shfl_down((int)P, d);
    if (lane + d > 63) q = ID;
    P = compose_map(P, q);
  }
  unsigned int E = (unsigned int)__shfl_down((int)P, 1);  // exclusive suffix
  if (lane == 63) E = ID;
  const int last = s_last;
  unsigned int tag = (E >> (8 * last)) & 3u;
  int* ob = out + (size_t)b * Tn;
  #pragma unroll
  for (int k = 15; k >= 0; --k) {
    tag = (mloc[k] >> (8 * tag)) & 3u;
    ob[t0 + k] = (int)tag;
  }
}

extern "C" void kernel_launch(void* const* d_in, const int* in_sizes, int n_in,
                              void* d_out, int out_size, void* d_ws, size_t ws_size,
                              hipStream_t stream) {
  const float* x      = (const float*)d_in[0];
  const float* conv_w = (const float*)d_in[1];
  const float* conv_b = (const float*)d_in[2];
  const float* lin_w  = (const float*)d_in[3];
  const float* lin_b  = (const float*)d_in[4];
  const float* cstart = (const float*)d_in[5];
  const float* cend   = (const float*)d_in[6];
  const float* ctrans = (const float*)d_in[7];
  int* out = (int*)d_out;

  float* wP = (float*)d_ws;                      // 768*256 floats
  float* em = wP + 768 * 256;                    // 64*1024*4 floats

  pack_w_k<<<768, 256, 0, stream>>>(conv_w, wP);
  emis_k<<<dim3(Tn / MROWS, Bn), 256, 0, stream>>>(x, wP, conv_b, lin_w, lin_b, em);
  viterbi_k<<<Bn, 64, 0, stream>>>(em, cstart, cend, ctrans, out);
}